// Round 1
// baseline (1021.901 us; speedup 1.0000x reference)
//
#include <hip/hip_runtime.h>
#include <math.h>

#define J_LEN 81
#define DIM 128
#define SCALE 0.17677669529663687f  // (128/4)^-0.5 = 1/sqrt(32)

// One wave per batch. Block = 4 waves = 4 batches. No __syncthreads at all:
// scores/softmax/PV are wave-local (LDS slice per wave, wave-synchronous).
// Every global load is a contiguous 1KB wave transaction (2 full 512B rows).
__global__ __launch_bounds__(256) void mhar_kernel(
    const float* __restrict__ Q,
    const float* __restrict__ K,
    const float* __restrict__ V,
    const float* __restrict__ Qr,
    const float* __restrict__ Kr,
    float* __restrict__ out,
    int B)
{
    const int t    = threadIdx.x;
    const int wave = t >> 6;
    const int lane = t & 63;
    const int b    = blockIdx.x * 4 + wave;
    if (b >= B) return;

    const int rsub = lane >> 5;   // which row of the 2-row pair this half-wave reads
    const int c    = lane & 31;   // float4 column within the 128-dim row (0..31)
    const int h    = c >> 3;      // head of this 32-dim chunk
    const int sub  = c & 7;       // float4 index within the head chunk

    __shared__ float s_sc[4][4][88];          // [wave][head][j], padded; [81..87] zeroed
    float (*sc)[88] = s_sc[wave];

    const float4* K4  = (const float4*)K;
    const float4* Kr4 = (const float4*)Kr;
    const float4* Qr4 = (const float4*)Qr;
    const float4* V4  = (const float4*)V;

    const size_t rowbase = (size_t)b * J_LEN;           // row index base
    const float4 q4 = ((const float4*)Q)[(size_t)b * 32 + c];

    // ---- Phase A: s[h][j] = SCALE * ( Q·(K+Kr) + Qr·K )  ----
    // Wave reads rows (2*jt+0, 2*jt+1) of K/Kr/Qr: 3 x 1KB contiguous per iter.
    for (int jt = 0; jt < 41; ++jt) {
        const int j  = jt * 2 + rsub;                   // 0..81
        const int jc = (j < J_LEN) ? j : (J_LEN - 1);   // clamp tail (L2 hit)
        const size_t idx = (rowbase + jc) * 32 + c;
        float4 k  = K4[idx];
        float4 kr = Kr4[idx];
        float4 qr = Qr4[idx];
        float p = q4.x * (k.x + kr.x) + qr.x * k.x
                + q4.y * (k.y + kr.y) + qr.y * k.y
                + q4.z * (k.z + kr.z) + qr.z * k.z
                + q4.w * (k.w + kr.w) + qr.w * k.w;
        p += __shfl_xor(p, 1);
        p += __shfl_xor(p, 2);
        p += __shfl_xor(p, 4);
        if (sub == 0 && j < J_LEN) sc[h][j] = p * SCALE;
    }
    asm volatile("" ::: "memory");   // wave-synchronous LDS: pin program order

    // ---- Softmax over j, per head (wave-local, heads serial) ----
    #pragma unroll
    for (int hh = 0; hh < 4; ++hh) {
        float s0 = sc[hh][lane];                                  // lane < 81 always
        float s1 = (lane + 64 < J_LEN) ? sc[hh][lane + 64] : -INFINITY;
        float m = fmaxf(s0, s1);
        #pragma unroll
        for (int off = 32; off > 0; off >>= 1)
            m = fmaxf(m, __shfl_xor(m, off));
        float e0 = __expf(s0 - m);
        float e1 = (lane + 64 < J_LEN) ? __expf(s1 - m) : 0.f;
        float sum = e0 + e1;
        #pragma unroll
        for (int off = 32; off > 0; off >>= 1)
            sum += __shfl_xor(sum, off);
        const float inv = 1.f / sum;
        sc[hh][lane] = e0 * inv;
        if (lane + 64 < 88) sc[hh][lane + 64] = e1 * inv;  // lanes 17..23 write the 0-pad
    }
    asm volatile("" ::: "memory");

    // ---- Phase B: out[c] = sum_j p[h][j] * V[j][c] ----
    // Wave reads rows (2*jt+0, 2*jt+1) of V: 1KB contiguous per iter.
    float4 acc = {0.f, 0.f, 0.f, 0.f};
    for (int jt = 0; jt < 41; ++jt) {
        const int j  = jt * 2 + rsub;                   // 0..81 (81 -> p = 0 pad)
        const int jc = (j < J_LEN) ? j : (J_LEN - 1);
        const float pw = sc[h][j];
        float4 v = V4[(rowbase + jc) * 32 + c];
        acc.x += pw * v.x;
        acc.y += pw * v.y;
        acc.z += pw * v.z;
        acc.w += pw * v.w;
    }
    // combine the two half-wave row-parities
    acc.x += __shfl_xor(acc.x, 32);
    acc.y += __shfl_xor(acc.y, 32);
    acc.z += __shfl_xor(acc.z, 32);
    acc.w += __shfl_xor(acc.w, 32);
    if (lane < 32)
        ((float4*)out)[(size_t)b * 32 + c] = acc;
}

extern "C" void kernel_launch(void* const* d_in, const int* in_sizes, int n_in,
                              void* d_out, int out_size, void* d_ws, size_t ws_size,
                              hipStream_t stream) {
    const float* Q  = (const float*)d_in[0];
    const float* K  = (const float*)d_in[1];
    const float* V  = (const float*)d_in[2];
    const float* Qr = (const float*)d_in[3];
    const float* Kr = (const float*)d_in[4];
    float* out = (float*)d_out;
    const int B = in_sizes[0] / DIM;  // 8192
    const int grid = (B + 3) / 4;
    mhar_kernel<<<grid, 256, 0, stream>>>(Q, K, V, Qr, Kr, out, B);
}